// Round 2
// baseline (398.827 us; speedup 1.0000x reference)
//
#include <hip/hip_runtime.h>
#include <hip/hip_bf16.h>

typedef __bf16 bf16_t;
typedef __bf16 bf16x2 __attribute__((ext_vector_type(2)));
typedef __bf16 bf16x4v __attribute__((ext_vector_type(4)));
typedef __bf16 bf16x8 __attribute__((ext_vector_type(8)));
typedef float f32x4 __attribute__((ext_vector_type(4)));

#define LOG2E 1.4426950408889634f

// ---------------- fp32 -> bf16 conversion ----------------
__global__ __launch_bounds__(256) void cvt_f32_bf16(const float* __restrict__ in,
                                                    bf16_t* __restrict__ out, int n4) {
  int i = blockIdx.x * 256 + threadIdx.x;
  if (i < n4) {
    float4 v = ((const float4*)in)[i];
    bf16x4v o;
    o[0] = (__bf16)v.x; o[1] = (__bf16)v.y; o[2] = (__bf16)v.z; o[3] = (__bf16)v.w;
    *(bf16x4v*)(out + (size_t)i * 4) = o;
  }
}

// ---------------- RoPE cos/sin tables: [S=2048][64] ----------------
__global__ __launch_bounds__(256) void rope_tables(float* __restrict__ cosT,
                                                   float* __restrict__ sinT) {
  int idx = blockIdx.x * 256 + threadIdx.x;   // 2048*64 = 131072
  int s = idx >> 6, i = idx & 63;
  float inv = __builtin_amdgcn_exp2f(-(float)i * (19.931568569324174f / 64.0f));
  float f = (float)s * inv;
  cosT[idx] = cosf(f);
  sinT[idx] = sinf(f);
}

// ---------------- bf16 NT GEMM: C[m,n] = sum_k A[m,k]*B[n,k], fp32 out ----------
__global__ __launch_bounds__(256) void gemm_nt(const bf16_t* __restrict__ A,
                                               const bf16_t* __restrict__ B,
                                               float* __restrict__ C,
                                               int M, int N, int K) {
  __shared__ bf16_t As[128 * 64];
  __shared__ bf16_t Bs[128 * 64];
  int nb = N >> 7;
  int bm = blockIdx.x / nb, bn = blockIdx.x % nb;
  int m0 = bm << 7, n0 = bn << 7;
  int tid = threadIdx.x, lane = tid & 63, wv = tid >> 6;
  int wr = wv >> 1, wc = wv & 1, lr = lane & 15, g = lane >> 4;

  f32x4 acc[4][4];
#pragma unroll
  for (int i = 0; i < 4; i++)
#pragma unroll
    for (int j = 0; j < 4; j++)
#pragma unroll
      for (int r = 0; r < 4; r++) acc[i][j][r] = 0.f;

  int srow = wv * 32 + (lane >> 3);
  int scol = (lane & 7) * 8;
  const bf16_t* aBase = A + (size_t)(m0 + srow) * K + scol;
  const bf16_t* bBase = B + (size_t)(n0 + srow) * K + scol;

  for (int k0 = 0; k0 < K; k0 += 64) {
#pragma unroll
    for (int i = 0; i < 4; i++) {
      __builtin_amdgcn_global_load_lds(
          (const __attribute__((address_space(1))) void*)(aBase + (size_t)i * 8 * K + k0),
          (__attribute__((address_space(3))) void*)&As[(wv * 32 + i * 8) * 64], 16, 0, 0);
      __builtin_amdgcn_global_load_lds(
          (const __attribute__((address_space(1))) void*)(bBase + (size_t)i * 8 * K + k0),
          (__attribute__((address_space(3))) void*)&Bs[(wv * 32 + i * 8) * 64], 16, 0, 0);
    }
    __syncthreads();
#pragma unroll
    for (int ks = 0; ks < 2; ks++) {
      bf16x8 af[4], bfv[4];
#pragma unroll
      for (int mi = 0; mi < 4; mi++)
        af[mi] = *(const bf16x8*)&As[(wr * 64 + mi * 16 + lr) * 64 + ks * 32 + g * 8];
#pragma unroll
      for (int ni = 0; ni < 4; ni++)
        bfv[ni] = *(const bf16x8*)&Bs[(wc * 64 + ni * 16 + lr) * 64 + ks * 32 + g * 8];
#pragma unroll
      for (int mi = 0; mi < 4; mi++)
#pragma unroll
        for (int ni = 0; ni < 4; ni++)
          acc[mi][ni] = __builtin_amdgcn_mfma_f32_16x16x32_bf16(af[mi], bfv[ni], acc[mi][ni], 0, 0, 0);
    }
    __syncthreads();
  }

#pragma unroll
  for (int mi = 0; mi < 4; mi++)
#pragma unroll
    for (int ni = 0; ni < 4; ni++) {
      int m = m0 + wr * 64 + mi * 16 + g * 4;
      int n = n0 + wc * 64 + ni * 16 + lr;
#pragma unroll
      for (int r = 0; r < 4; r++) C[(size_t)(m + r) * N + n] = acc[mi][ni][r];
    }
}

// ---------------- fused per-head LayerNorm + RoPE -> bf16 Q(B,H,S,D), K(B,KV,S,D) ----
__global__ __launch_bounds__(256) void ln_rope(const float* __restrict__ qkv,
                                               const float* __restrict__ qw, const float* __restrict__ qb,
                                               const float* __restrict__ kw, const float* __restrict__ kb,
                                               const float* __restrict__ cosT, const float* __restrict__ sinT,
                                               bf16_t* __restrict__ Qr, bf16_t* __restrict__ Kr) {
  int row = blockIdx.x;              // b*2048 + s
  int b = row >> 11, s = row & 2047;
  int lane = threadIdx.x & 63, wv = threadIdx.x >> 6;
  float c = cosT[(s << 6) + lane], sn = sinT[(s << 6) + lane];
  const float* base = qkv + (size_t)row * 5120;
#pragma unroll
  for (int i = 0; i < 5; i++) {
    int head = wv * 5 + i;           // 0..15 = q heads, 16..19 = k heads
    bool isq = head < 16;
    int off = isq ? (head << 7) : (4096 + ((head - 16) << 7));
    float2 x = *(const float2*)(base + off + (lane << 1));
    float sum = x.x + x.y;
#pragma unroll
    for (int m = 1; m < 64; m <<= 1) sum += __shfl_xor(sum, m);
    float mu = sum * 0.0078125f;
    float x0 = x.x - mu, x1 = x.y - mu;
    float vs = x0 * x0 + x1 * x1;
#pragma unroll
    for (int m = 1; m < 64; m <<= 1) vs += __shfl_xor(vs, m);
    float rs = rsqrtf(vs * 0.0078125f + 1e-6f);
    const float* w = isq ? qw : kw;
    const float* bb = isq ? qb : kb;
    float y0 = x0 * rs * w[lane << 1] + bb[lane << 1];
    float y1 = x1 * rs * w[(lane << 1) + 1] + bb[(lane << 1) + 1];
    float o0 = y0 * c - y1 * sn;
    float o1 = y0 * sn + y1 * c;
    bf16x2 ov; ov[0] = (__bf16)o0; ov[1] = (__bf16)o1;
    size_t dst = isq ? ((((size_t)(b * 16 + head)) * 2048 + s) * 128 + (lane << 1))
                     : ((((size_t)(b * 4 + (head - 16))) * 2048 + s) * 128 + (lane << 1));
    *(bf16x2*)((isq ? Qr : Kr) + dst) = ov;
  }
}

// ---------------- V transpose: qkv v-slice (B,S,KV,D) -> Vt (B,KV,D,S) bf16 -------
__global__ __launch_bounds__(256) void vtrans(const float* __restrict__ qkv,
                                              bf16_t* __restrict__ Vt) {
  int bid = blockIdx.x;              // ((b*4+kv)*64 + sb)
  int sb = bid & 63, kv = (bid >> 6) & 3, b = bid >> 8;
  int s0 = sb << 5;
  __shared__ bf16_t T[128 * 33];
  int tid = threadIdx.x;
#pragma unroll
  for (int i = 0; i < 16; i++) {
    int idx = i * 256 + tid;         // 0..4095
    int r = idx >> 7, d = idx & 127;
    float v = qkv[((size_t)(b * 2048 + s0 + r)) * 5120 + 4608 + (kv << 7) + d];
    T[d * 33 + r] = (__bf16)v;
  }
  __syncthreads();
#pragma unroll
  for (int j = 0; j < 16; j++) {
    int idx = j * 256 + tid;
    int d = idx >> 5, sc = idx & 31;
    Vt[(((size_t)(b * 4 + kv)) * 128 + d) * 2048 + s0 + sc] = T[d * 33 + sc];
  }
}

// ---------------- causal GQA flash attention + sigmoid gate -> ag bf16 (B,S,H*D) ----
__device__ __forceinline__ int fsw(int r) { return (r & 3) | ((r & 8) >> 1); }

__device__ __forceinline__ void sm_update(const f32x4& s0, const f32x4& s1,
                                          int qrow, int kvabs,
                                          float& mrun, float& lsum,
                                          bf16x8& pb, f32x4 (&oac)[8]) {
  const float K2 = 0.08838834764831843f * LOG2E;   // (1/sqrt(128)) * log2(e)
  float tt[8];
#pragma unroll
  for (int r = 0; r < 4; r++) {
    tt[r]     = (kvabs + r     <= qrow) ? s0[r] * K2 : -1e30f;
    tt[4 + r] = (kvabs + 4 + r <= qrow) ? s1[r] * K2 : -1e30f;
  }
  float pm = tt[0];
#pragma unroll
  for (int i = 1; i < 8; i++) pm = fmaxf(pm, tt[i]);
  pm = fmaxf(pm, __shfl_xor(pm, 16));
  pm = fmaxf(pm, __shfl_xor(pm, 32));
  if (__all(pm <= mrun + 8.f)) {     // defer-max: skip O rescale (T13)
    float ps = 0.f;
#pragma unroll
    for (int i = 0; i < 8; i++) {
      float pv = __builtin_amdgcn_exp2f(tt[i] - mrun);
      pb[i] = (__bf16)pv; ps += pv;
    }
    ps += __shfl_xor(ps, 16); ps += __shfl_xor(ps, 32);
    lsum += ps;
  } else {
    float mnew = fmaxf(mrun, pm);
    float corr = __builtin_amdgcn_exp2f(mrun - mnew);
    float ps = 0.f;
#pragma unroll
    for (int i = 0; i < 8; i++) {
      float pv = __builtin_amdgcn_exp2f(tt[i] - mnew);
      pb[i] = (__bf16)pv; ps += pv;
    }
    ps += __shfl_xor(ps, 16); ps += __shfl_xor(ps, 32);
    lsum = lsum * corr + ps;
    mrun = mnew;
#pragma unroll
    for (int dt = 0; dt < 8; dt++)
#pragma unroll
      for (int r = 0; r < 4; r++) oac[dt][r] *= corr;
  }
}

// block: 4 waves; waves 0,1 -> q-group j (rows 64j..64j+63), waves 2,3 -> q-group 31-j.
// Each wave owns 32 q rows (2 q-frags of 16). KV tile 64, double-buffered async staging.
__global__ __launch_bounds__(256) void attn(const bf16_t* __restrict__ Qr,
                                            const bf16_t* __restrict__ Kr,
                                            const bf16_t* __restrict__ Vt,
                                            const float* __restrict__ qkv,
                                            bf16_t* __restrict__ ag) {
  __shared__ bf16_t Ks[2 * 64 * 128];   // 32 KB: K tiles, chunk-XOR swizzled
  __shared__ bf16_t Vs[2 * 128 * 64];   // 32 KB: V^T tiles, XOR-by-row swizzled
  int bid = blockIdx.x;                 // 512 = 16h * 2b * 16j
  int h = bid & 15, b = (bid >> 4) & 1, j = bid >> 5;
  int kvh = h >> 2;
  int tid = threadIdx.x, lane = tid & 63, wv = tid >> 6;
  int lr = lane & 15, g = lane >> 4;
  int qg = (wv >> 1) ? (31 - j) : j;    // 64-row q-group index
  int qw = (qg << 6) + ((wv & 1) << 5); // wave q base (32 rows)
  int qrow0 = qw + lr, qrow1 = qrow0 + 16;
  int maxq = qw + 31;
  int ntiles = 32 - j;                  // kv tiles staged (covers both groups)

  const bf16_t* Qg0 = Qr + (((size_t)(b * 16 + h)) * 2048 + qrow0) * 128;
  bf16x8 qf0[4], qf1[4];
#pragma unroll
  for (int ds = 0; ds < 4; ds++) {
    qf0[ds] = *(const bf16x8*)(Qg0 + ds * 32 + g * 8);
    qf1[ds] = *(const bf16x8*)(Qg0 + 16 * 128 + ds * 32 + g * 8);
  }
  const bf16_t* Kg = Kr + ((size_t)(b * 4 + kvh)) * 2048 * 128;
  const bf16_t* Vg = Vt + ((size_t)(b * 4 + kvh)) * 128 * 2048;

  // per-thread staging source offsets (pre-swizzled global addresses, linear LDS dest)
  int kOff[4], vOff[4];
#pragma unroll
  for (int rnd = 0; rnd < 4; rnd++) {
    int o = rnd * 4096 + wv * 1024 + lane * 16;   // byte offset in 16KB tile
    int r = o >> 8, cp = (o >> 4) & 15;           // K: 256B rows
    kOff[rnd] = r * 128 + ((cp ^ fsw(r)) << 3);
    int d = o >> 7, cv = (o >> 4) & 7;            // V: 128B rows
    vOff[rnd] = d * 2048 + ((cv ^ (d & 7)) << 3);
  }

  auto stage = [&](int buf, int kv0) {
    char* kb = (char*)Ks + buf * 16384 + wv * 1024;
    char* vb = (char*)Vs + buf * 16384 + wv * 1024;
#pragma unroll
    for (int rnd = 0; rnd < 4; rnd++)
      __builtin_amdgcn_global_load_lds(
          (const __attribute__((address_space(1))) void*)(Kg + (size_t)kv0 * 128 + kOff[rnd]),
          (__attribute__((address_space(3))) void*)(kb + rnd * 4096), 16, 0, 0);
#pragma unroll
    for (int rnd = 0; rnd < 4; rnd++)
      __builtin_amdgcn_global_load_lds(
          (const __attribute__((address_space(1))) void*)(Vg + kv0 + vOff[rnd]),
          (__attribute__((address_space(3))) void*)(vb + rnd * 4096), 16, 0, 0);
  };

  f32x4 oa0[8], oa1[8];
#pragma unroll
  for (int i = 0; i < 8; i++)
#pragma unroll
    for (int r = 0; r < 4; r++) { oa0[i][r] = 0.f; oa1[i][r] = 0.f; }
  float mrun0 = -1e30f, mrun1 = -1e30f, lsum0 = 0.f, lsum1 = 0.f;

  int r0base = ((lr >> 2) << 3) + (lr & 3);       // pi(lr)

  stage(0, 0);
  for (int t = 0; t < ntiles; t++) {
    int cur = t & 1;
    if (t + 1 < ntiles) {
      stage(cur ^ 1, (t + 1) << 6);
      asm volatile("s_waitcnt vmcnt(8)" ::: "memory");   // cur buffer done; next in flight
    } else {
      asm volatile("s_waitcnt vmcnt(0)" ::: "memory");
    }
    __builtin_amdgcn_s_barrier();
    int kv0 = t << 6;
    if (kv0 <= maxq) {
      const bf16_t* ksb = Ks + cur * 8192;
      const bf16_t* vsb = Vs + cur * 8192;
#pragma unroll
      for (int ss = 0; ss < 2; ss++) {
        int kvb = ss << 5;
        int r0 = kvb + r0base, r1 = r0 + 4;
        int f0 = fsw(r0), f1 = fsw(r1);
        f32x4 s00, s10, s01, s11;
#pragma unroll
        for (int r = 0; r < 4; r++) { s00[r] = 0.f; s10[r] = 0.f; s01[r] = 0.f; s11[r] = 0.f; }
        __builtin_amdgcn_s_setprio(1);
#pragma unroll
        for (int ds = 0; ds < 4; ds++) {
          bf16x8 a0 = *(const bf16x8*)&ksb[r0 * 128 + (((ds * 4 + g) ^ f0) << 3)];
          bf16x8 a1 = *(const bf16x8*)&ksb[r1 * 128 + (((ds * 4 + g) ^ f1) << 3)];
          s00 = __builtin_amdgcn_mfma_f32_16x16x32_bf16(a0, qf0[ds], s00, 0, 0, 0);
          s10 = __builtin_amdgcn_mfma_f32_16x16x32_bf16(a1, qf0[ds], s10, 0, 0, 0);
          s01 = __builtin_amdgcn_mfma_f32_16x16x32_bf16(a0, qf1[ds], s01, 0, 0, 0);
          s11 = __builtin_amdgcn_mfma_f32_16x16x32_bf16(a1, qf1[ds], s11, 0, 0, 0);
        }
        __builtin_amdgcn_s_setprio(0);
        int kvabs = kv0 + kvb + (g << 3);
        bf16x8 pb0, pb1;
        sm_update(s00, s10, qrow0, kvabs, mrun0, lsum0, pb0, oa0);
        sm_update(s01, s11, qrow1, kvabs, mrun1, lsum1, pb1, oa1);
        __builtin_amdgcn_s_setprio(1);
#pragma unroll
        for (int dt = 0; dt < 8; dt++) {
          bf16x8 va = *(const bf16x8*)&vsb[(dt * 16 + lr) * 64 + (((ss * 4 + g) ^ (lr & 7)) << 3)];
          oa0[dt] = __builtin_amdgcn_mfma_f32_16x16x32_bf16(va, pb0, oa0[dt], 0, 0, 0);
          oa1[dt] = __builtin_amdgcn_mfma_f32_16x16x32_bf16(va, pb1, oa1[dt], 0, 0, 0);
        }
        __builtin_amdgcn_s_setprio(0);
      }
    }
    asm volatile("s_waitcnt lgkmcnt(0)" ::: "memory");   // this wave's ds_reads done
    __builtin_amdgcn_s_barrier();                        // before next stage overwrites
  }

  float invl0 = 1.0f / lsum0, invl1 = 1.0f / lsum1;
  size_t ob0 = ((size_t)b * 2048 + qrow0) * 2048 + (h << 7);
  size_t gb0 = ((size_t)b * 2048 + qrow0) * 5120 + 2048 + (h << 7);
  size_t ob1 = ((size_t)b * 2048 + qrow1) * 2048 + (h << 7);
  size_t gb1 = ((size_t)b * 2048 + qrow1) * 5120 + 2048 + (h << 7);
#pragma unroll
  for (int dt = 0; dt < 8; dt++) {
    int d = dt * 16 + (g << 2);
    float4 gt0 = *(const float4*)(qkv + gb0 + d);
    float4 gt1 = *(const float4*)(qkv + gb1 + d);
    bf16x4v o0, o1;
    o0[0] = (__bf16)(oa0[dt][0] * invl0 / (1.f + __builtin_amdgcn_exp2f(-gt0.x * LOG2E)));
    o0[1] = (__bf16)(oa0[dt][1] * invl0 / (1.f + __builtin_amdgcn_exp2f(-gt0.y * LOG2E)));
    o0[2] = (__bf16)(oa0[dt][2] * invl0 / (1.f + __builtin_amdgcn_exp2f(-gt0.z * LOG2E)));
    o0[3] = (__bf16)(oa0[dt][3] * invl0 / (1.f + __builtin_amdgcn_exp2f(-gt0.w * LOG2E)));
    o1[0] = (__bf16)(oa1[dt][0] * invl1 / (1.f + __builtin_amdgcn_exp2f(-gt1.x * LOG2E)));
    o1[1] = (__bf16)(oa1[dt][1] * invl1 / (1.f + __builtin_amdgcn_exp2f(-gt1.y * LOG2E)));
    o1[2] = (__bf16)(oa1[dt][2] * invl1 / (1.f + __builtin_amdgcn_exp2f(-gt1.z * LOG2E)));
    o1[3] = (__bf16)(oa1[dt][3] * invl1 / (1.f + __builtin_amdgcn_exp2f(-gt1.w * LOG2E)));
    *(bf16x4v*)(ag + ob0 + d) = o0;
    *(bf16x4v*)(ag + ob1 + d) = o1;
  }
}

// ---------------- launch ----------------
extern "C" void kernel_launch(void* const* d_in, const int* in_sizes, int n_in,
                              void* d_out, int out_size, void* d_ws, size_t ws_size,
                              hipStream_t stream) {
  const float* x    = (const float*)d_in[0];
  const float* wqkv = (const float*)d_in[1];
  const float* wo   = (const float*)d_in[2];
  const float* qnw  = (const float*)d_in[3];
  const float* qnb  = (const float*)d_in[4];
  const float* knw  = (const float*)d_in[5];
  const float* knb  = (const float*)d_in[6];
  float* out = (float*)d_out;

  char* p = (char*)d_ws;
  bf16_t* xb  = (bf16_t*)p;           // 16 MB, reused as ag after GEMM1
  bf16_t* ag  = xb;
  p += (size_t)16777216;
  bf16_t* wqb = (bf16_t*)p;           // 20 MB, reused as Qr after GEMM1
  bf16_t* Qr  = wqb;
  p += (size_t)20971520;
  bf16_t* wob = (bf16_t*)p; p += (size_t)8388608;
  float*  qkv = (float*)p;  p += (size_t)83886080;
  bf16_t* Kr  = (bf16_t*)p; p += (size_t)4194304;
  bf16_t* Vt  = (bf16_t*)p; p += (size_t)4194304;
  float* cosT = (float*)p;  p += (size_t)524288;
  float* sinT = (float*)p;  p += (size_t)524288;

  cvt_f32_bf16<<<8192, 256, 0, stream>>>(x, xb, 2097152);
  cvt_f32_bf16<<<10240, 256, 0, stream>>>(wqkv, wqb, 2621440);
  cvt_f32_bf16<<<4096, 256, 0, stream>>>(wo, wob, 1048576);
  rope_tables<<<512, 256, 0, stream>>>(cosT, sinT);

  // qkv = x @ w_qkv^T   (4096 x 5120 x K=2048)
  gemm_nt<<<1280, 256, 0, stream>>>(xb, wqb, qkv, 4096, 5120, 2048);

  ln_rope<<<4096, 256, 0, stream>>>(qkv, qnw, qnb, knw, knb, cosT, sinT, Qr, Kr);
  vtrans<<<512, 256, 0, stream>>>(qkv, Vt);

  attn<<<512, 256, 0, stream>>>(Qr, Kr, Vt, qkv, ag);

  // out = ag @ w_o^T    (4096 x 2048 x K=2048)
  gemm_nt<<<512, 256, 0, stream>>>(ag, wob, out, 4096, 2048, 2048);
}

// Round 3
// 395.801 us; speedup vs baseline: 1.0076x; 1.0076x over previous
//
#include <hip/hip_runtime.h>
#include <hip/hip_bf16.h>

typedef __bf16 bf16_t;
typedef __bf16 bf16x2 __attribute__((ext_vector_type(2)));
typedef __bf16 bf16x4v __attribute__((ext_vector_type(4)));
typedef __bf16 bf16x8 __attribute__((ext_vector_type(8)));
typedef float f32x4 __attribute__((ext_vector_type(4)));

#define LOG2E 1.4426950408889634f

// ---------------- fp32 -> bf16 conversion ----------------
__global__ __launch_bounds__(256) void cvt_f32_bf16(const float* __restrict__ in,
                                                    bf16_t* __restrict__ out, int n4) {
  int i = blockIdx.x * 256 + threadIdx.x;
  if (i < n4) {
    float4 v = ((const float4*)in)[i];
    bf16x4v o;
    o[0] = (__bf16)v.x; o[1] = (__bf16)v.y; o[2] = (__bf16)v.z; o[3] = (__bf16)v.w;
    *(bf16x4v*)(out + (size_t)i * 4) = o;
  }
}

// ---------------- RoPE cos/sin tables: [S=2048][64] ----------------
__global__ __launch_bounds__(256) void rope_tables(float* __restrict__ cosT,
                                                   float* __restrict__ sinT) {
  int idx = blockIdx.x * 256 + threadIdx.x;   // 2048*64 = 131072
  int s = idx >> 6, i = idx & 63;
  float inv = __builtin_amdgcn_exp2f(-(float)i * (19.931568569324174f / 64.0f));
  float f = (float)s * inv;
  cosT[idx] = cosf(f);
  sinT[idx] = sinf(f);
}

// ---------------- bf16 NT GEMM: C[m,n] = sum_k A[m,k]*B[n,k], fp32 out ----------
__global__ __launch_bounds__(256) void gemm_nt(const bf16_t* __restrict__ A,
                                               const bf16_t* __restrict__ B,
                                               float* __restrict__ C,
                                               int M, int N, int K) {
  __shared__ bf16_t As[128 * 64];
  __shared__ bf16_t Bs[128 * 64];
  int nb = N >> 7;
  int bm = blockIdx.x / nb, bn = blockIdx.x % nb;
  int m0 = bm << 7, n0 = bn << 7;
  int tid = threadIdx.x, lane = tid & 63, wv = tid >> 6;
  int wr = wv >> 1, wc = wv & 1, lr = lane & 15, g = lane >> 4;

  f32x4 acc[4][4];
#pragma unroll
  for (int i = 0; i < 4; i++)
#pragma unroll
    for (int j = 0; j < 4; j++)
#pragma unroll
      for (int r = 0; r < 4; r++) acc[i][j][r] = 0.f;

  int srow = wv * 32 + (lane >> 3);
  int scol = (lane & 7) * 8;
  const bf16_t* aBase = A + (size_t)(m0 + srow) * K + scol;
  const bf16_t* bBase = B + (size_t)(n0 + srow) * K + scol;

  for (int k0 = 0; k0 < K; k0 += 64) {
#pragma unroll
    for (int i = 0; i < 4; i++) {
      __builtin_amdgcn_global_load_lds(
          (const __attribute__((address_space(1))) void*)(aBase + (size_t)i * 8 * K + k0),
          (__attribute__((address_space(3))) void*)&As[(wv * 32 + i * 8) * 64], 16, 0, 0);
      __builtin_amdgcn_global_load_lds(
          (const __attribute__((address_space(1))) void*)(bBase + (size_t)i * 8 * K + k0),
          (__attribute__((address_space(3))) void*)&Bs[(wv * 32 + i * 8) * 64], 16, 0, 0);
    }
    __syncthreads();
#pragma unroll
    for (int ks = 0; ks < 2; ks++) {
      bf16x8 af[4], bfv[4];
#pragma unroll
      for (int mi = 0; mi < 4; mi++)
        af[mi] = *(const bf16x8*)&As[(wr * 64 + mi * 16 + lr) * 64 + ks * 32 + g * 8];
#pragma unroll
      for (int ni = 0; ni < 4; ni++)
        bfv[ni] = *(const bf16x8*)&Bs[(wc * 64 + ni * 16 + lr) * 64 + ks * 32 + g * 8];
#pragma unroll
      for (int mi = 0; mi < 4; mi++)
#pragma unroll
        for (int ni = 0; ni < 4; ni++)
          acc[mi][ni] = __builtin_amdgcn_mfma_f32_16x16x32_bf16(af[mi], bfv[ni], acc[mi][ni], 0, 0, 0);
    }
    __syncthreads();
  }

#pragma unroll
  for (int mi = 0; mi < 4; mi++)
#pragma unroll
    for (int ni = 0; ni < 4; ni++) {
      int m = m0 + wr * 64 + mi * 16 + g * 4;
      int n = n0 + wc * 64 + ni * 16 + lr;
#pragma unroll
      for (int r = 0; r < 4; r++) C[(size_t)(m + r) * N + n] = acc[mi][ni][r];
    }
}

// ---------------- fused per-head LayerNorm + RoPE -> bf16 Q(B,H,S,D), K(B,KV,S,D) ----
__global__ __launch_bounds__(256) void ln_rope(const float* __restrict__ qkv,
                                               const float* __restrict__ qw, const float* __restrict__ qb,
                                               const float* __restrict__ kw, const float* __restrict__ kb,
                                               const float* __restrict__ cosT, const float* __restrict__ sinT,
                                               bf16_t* __restrict__ Qr, bf16_t* __restrict__ Kr) {
  int row = blockIdx.x;              // b*2048 + s
  int b = row >> 11, s = row & 2047;
  int lane = threadIdx.x & 63, wv = threadIdx.x >> 6;
  float c = cosT[(s << 6) + lane], sn = sinT[(s << 6) + lane];
  const float* base = qkv + (size_t)row * 5120;
#pragma unroll
  for (int i = 0; i < 5; i++) {
    int head = wv * 5 + i;           // 0..15 = q heads, 16..19 = k heads
    bool isq = head < 16;
    int off = isq ? (head << 7) : (4096 + ((head - 16) << 7));
    float2 x = *(const float2*)(base + off + (lane << 1));
    float sum = x.x + x.y;
#pragma unroll
    for (int m = 1; m < 64; m <<= 1) sum += __shfl_xor(sum, m);
    float mu = sum * 0.0078125f;
    float x0 = x.x - mu, x1 = x.y - mu;
    float vs = x0 * x0 + x1 * x1;
#pragma unroll
    for (int m = 1; m < 64; m <<= 1) vs += __shfl_xor(vs, m);
    float rs = rsqrtf(vs * 0.0078125f + 1e-6f);
    const float* w = isq ? qw : kw;
    const float* bb = isq ? qb : kb;
    float y0 = x0 * rs * w[lane << 1] + bb[lane << 1];
    float y1 = x1 * rs * w[(lane << 1) + 1] + bb[(lane << 1) + 1];
    float o0 = y0 * c - y1 * sn;
    float o1 = y0 * sn + y1 * c;
    bf16x2 ov; ov[0] = (__bf16)o0; ov[1] = (__bf16)o1;
    size_t dst = isq ? ((((size_t)(b * 16 + head)) * 2048 + s) * 128 + (lane << 1))
                     : ((((size_t)(b * 4 + (head - 16))) * 2048 + s) * 128 + (lane << 1));
    *(bf16x2*)((isq ? Qr : Kr) + dst) = ov;
  }
}

// ---------------- V transpose: qkv v-slice (B,S,KV,D) -> Vt (B,KV,D,S) bf16 -------
__global__ __launch_bounds__(256) void vtrans(const float* __restrict__ qkv,
                                              bf16_t* __restrict__ Vt) {
  int bid = blockIdx.x;              // ((b*4+kv)*64 + sb)
  int sb = bid & 63, kv = (bid >> 6) & 3, b = bid >> 8;
  int s0 = sb << 5;
  __shared__ bf16_t T[128 * 33];
  int tid = threadIdx.x;
#pragma unroll
  for (int i = 0; i < 16; i++) {
    int idx = i * 256 + tid;         // 0..4095
    int r = idx >> 7, d = idx & 127;
    float v = qkv[((size_t)(b * 2048 + s0 + r)) * 5120 + 4608 + (kv << 7) + d];
    T[d * 33 + r] = (__bf16)v;
  }
  __syncthreads();
#pragma unroll
  for (int j = 0; j < 16; j++) {
    int idx = j * 256 + tid;
    int d = idx >> 5, sc = idx & 31;
    Vt[(((size_t)(b * 4 + kv)) * 128 + d) * 2048 + s0 + sc] = T[d * 33 + sc];
  }
}

// ---------------- causal GQA flash attention + sigmoid gate -> ag bf16 (B,S,H*D) ----
__device__ __forceinline__ void sm_update(const f32x4& s0, const f32x4& s1,
                                          int qrow, int kvabs,
                                          float& mrun, float& lsum,
                                          bf16x8& pb, f32x4 (&oac)[8]) {
  const float K2 = 0.08838834764831843f * LOG2E;   // (1/sqrt(128)) * log2(e)
  float tt[8];
#pragma unroll
  for (int r = 0; r < 4; r++) {
    tt[r]     = (kvabs + r     <= qrow) ? s0[r] * K2 : -1e30f;
    tt[4 + r] = (kvabs + 4 + r <= qrow) ? s1[r] * K2 : -1e30f;
  }
  float pm = tt[0];
#pragma unroll
  for (int i = 1; i < 8; i++) pm = fmaxf(pm, tt[i]);
  pm = fmaxf(pm, __shfl_xor(pm, 16));
  pm = fmaxf(pm, __shfl_xor(pm, 32));
  if (__all(pm <= mrun + 8.f)) {     // defer-max: skip O rescale (T13)
    float ps = 0.f;
#pragma unroll
    for (int i = 0; i < 8; i++) {
      float pv = __builtin_amdgcn_exp2f(tt[i] - mrun);
      pb[i] = (__bf16)pv; ps += pv;
    }
    ps += __shfl_xor(ps, 16); ps += __shfl_xor(ps, 32);
    lsum += ps;
  } else {
    float mnew = fmaxf(mrun, pm);
    float corr = __builtin_amdgcn_exp2f(mrun - mnew);
    float ps = 0.f;
#pragma unroll
    for (int i = 0; i < 8; i++) {
      float pv = __builtin_amdgcn_exp2f(tt[i] - mnew);
      pb[i] = (__bf16)pv; ps += pv;
    }
    ps += __shfl_xor(ps, 16); ps += __shfl_xor(ps, 32);
    lsum = lsum * corr + ps;
    mrun = mnew;
#pragma unroll
    for (int dt = 0; dt < 8; dt++)
#pragma unroll
      for (int r = 0; r < 4; r++) oac[dt][r] *= corr;
  }
}

// No-LDS, no-barrier flash attention: each wave independently owns 32 q rows.
// K/V are L2-resident (1 MB per (b,kvh), shared by 128 wave-tasks) -> direct
// global fragment loads, latency hidden by 8 waves/CU + deep per-wave ILP.
// Block's 4 waves take q-groups {2j, 2j+1, 63-2j, 62-2j} for causal balance.
__global__ __launch_bounds__(256) void attn(const bf16_t* __restrict__ Qr,
                                            const bf16_t* __restrict__ Kr,
                                            const bf16_t* __restrict__ Vt,
                                            const float* __restrict__ qkv,
                                            bf16_t* __restrict__ ag) {
  int bid = blockIdx.x;                 // 512 = 16h * 2b * 16jj
  int h = bid & 15, b = (bid >> 4) & 1, jj = bid >> 5;
  int kvh = h >> 2;
  int tid = threadIdx.x, lane = tid & 63, wv = tid >> 6;
  int lr = lane & 15, g = lane >> 4;
  int qg = (wv & 2) ? (63 - 2 * jj - (wv & 1)) : (2 * jj + (wv & 1));
  int qw = qg << 5;                     // wave q base (32 rows)
  int qrow0 = qw + lr, qrow1 = qrow0 + 16;
  int maxq = qw + 31;
  int ntiles = (qg >> 1) + 1;           // 64-wide kv tiles

  const bf16_t* Qg0 = Qr + (((size_t)(b * 16 + h)) * 2048 + qrow0) * 128;
  bf16x8 qf0[4], qf1[4];
#pragma unroll
  for (int ds = 0; ds < 4; ds++) {
    qf0[ds] = *(const bf16x8*)(Qg0 + ds * 32 + g * 8);
    qf1[ds] = *(const bf16x8*)(Qg0 + 16 * 128 + ds * 32 + g * 8);
  }
  const bf16_t* Kg = Kr + ((size_t)(b * 4 + kvh)) * 2048 * 128;
  const bf16_t* Vg = Vt + ((size_t)(b * 4 + kvh)) * 128 * 2048;

  f32x4 oa0[8], oa1[8];
#pragma unroll
  for (int i = 0; i < 8; i++)
#pragma unroll
    for (int r = 0; r < 4; r++) { oa0[i][r] = 0.f; oa1[i][r] = 0.f; }
  float mrun0 = -1e30f, mrun1 = -1e30f, lsum0 = 0.f, lsum1 = 0.f;

  int r0base = ((lr >> 2) << 3) + (lr & 3);       // pi(lr): A-row -> K-row map

  for (int t = 0; t < ntiles; t++) {
    int kv0 = t << 6;
#pragma unroll
    for (int ss = 0; ss < 2; ss++) {
      int kvb = kv0 + (ss << 5);
      if (kvb <= maxq) {
        // K fragments: lane reads K[kvb + pi(lr) (+4)][ds*32 + g*8 ..+7]
        const bf16_t* kp = Kg + (size_t)(kvb + r0base) * 128 + g * 8;
        bf16x8 a0[4], a1[4];
#pragma unroll
        for (int ds = 0; ds < 4; ds++) {
          a0[ds] = *(const bf16x8*)(kp + ds * 32);
          a1[ds] = *(const bf16x8*)(kp + 4 * 128 + ds * 32);
        }
        // V^T fragments (issued before softmax; independent of it)
        const bf16_t* vp = Vg + (size_t)lr * 2048 + kvb + g * 8;
        bf16x8 va[8];
#pragma unroll
        for (int dt = 0; dt < 8; dt++)
          va[dt] = *(const bf16x8*)(vp + (size_t)dt * 16 * 2048);

        f32x4 s00, s10, s01, s11;
#pragma unroll
        for (int r = 0; r < 4; r++) { s00[r] = 0.f; s10[r] = 0.f; s01[r] = 0.f; s11[r] = 0.f; }
        __builtin_amdgcn_s_setprio(1);
#pragma unroll
        for (int ds = 0; ds < 4; ds++) {
          s00 = __builtin_amdgcn_mfma_f32_16x16x32_bf16(a0[ds], qf0[ds], s00, 0, 0, 0);
          s10 = __builtin_amdgcn_mfma_f32_16x16x32_bf16(a1[ds], qf0[ds], s10, 0, 0, 0);
          s01 = __builtin_amdgcn_mfma_f32_16x16x32_bf16(a0[ds], qf1[ds], s01, 0, 0, 0);
          s11 = __builtin_amdgcn_mfma_f32_16x16x32_bf16(a1[ds], qf1[ds], s11, 0, 0, 0);
        }
        __builtin_amdgcn_s_setprio(0);
        int kvabs = kvb + (g << 3);
        bf16x8 pb0, pb1;
        sm_update(s00, s10, qrow0, kvabs, mrun0, lsum0, pb0, oa0);
        sm_update(s01, s11, qrow1, kvabs, mrun1, lsum1, pb1, oa1);
        __builtin_amdgcn_s_setprio(1);
#pragma unroll
        for (int dt = 0; dt < 8; dt++) {
          oa0[dt] = __builtin_amdgcn_mfma_f32_16x16x32_bf16(va[dt], pb0, oa0[dt], 0, 0, 0);
          oa1[dt] = __builtin_amdgcn_mfma_f32_16x16x32_bf16(va[dt], pb1, oa1[dt], 0, 0, 0);
        }
        __builtin_amdgcn_s_setprio(0);
      }
    }
  }

  float invl0 = 1.0f / lsum0, invl1 = 1.0f / lsum1;
  size_t ob0 = ((size_t)b * 2048 + qrow0) * 2048 + (h << 7);
  size_t gb0 = ((size_t)b * 2048 + qrow0) * 5120 + 2048 + (h << 7);
  size_t ob1 = ((size_t)b * 2048 + qrow1) * 2048 + (h << 7);
  size_t gb1 = ((size_t)b * 2048 + qrow1) * 5120 + 2048 + (h << 7);
#pragma unroll
  for (int dt = 0; dt < 8; dt++) {
    int d = dt * 16 + (g << 2);
    float4 gt0 = *(const float4*)(qkv + gb0 + d);
    float4 gt1 = *(const float4*)(qkv + gb1 + d);
    bf16x4v o0, o1;
    o0[0] = (__bf16)(oa0[dt][0] * invl0 / (1.f + __builtin_amdgcn_exp2f(-gt0.x * LOG2E)));
    o0[1] = (__bf16)(oa0[dt][1] * invl0 / (1.f + __builtin_amdgcn_exp2f(-gt0.y * LOG2E)));
    o0[2] = (__bf16)(oa0[dt][2] * invl0 / (1.f + __builtin_amdgcn_exp2f(-gt0.z * LOG2E)));
    o0[3] = (__bf16)(oa0[dt][3] * invl0 / (1.f + __builtin_amdgcn_exp2f(-gt0.w * LOG2E)));
    o1[0] = (__bf16)(oa1[dt][0] * invl1 / (1.f + __builtin_amdgcn_exp2f(-gt1.x * LOG2E)));
    o1[1] = (__bf16)(oa1[dt][1] * invl1 / (1.f + __builtin_amdgcn_exp2f(-gt1.y * LOG2E)));
    o1[2] = (__bf16)(oa1[dt][2] * invl1 / (1.f + __builtin_amdgcn_exp2f(-gt1.z * LOG2E)));
    o1[3] = (__bf16)(oa1[dt][3] * invl1 / (1.f + __builtin_amdgcn_exp2f(-gt1.w * LOG2E)));
    *(bf16x4v*)(ag + ob0 + d) = o0;
    *(bf16x4v*)(ag + ob1 + d) = o1;
  }
}

// ---------------- launch ----------------
extern "C" void kernel_launch(void* const* d_in, const int* in_sizes, int n_in,
                              void* d_out, int out_size, void* d_ws, size_t ws_size,
                              hipStream_t stream) {
  const float* x    = (const float*)d_in[0];
  const float* wqkv = (const float*)d_in[1];
  const float* wo   = (const float*)d_in[2];
  const float* qnw  = (const float*)d_in[3];
  const float* qnb  = (const float*)d_in[4];
  const float* knw  = (const float*)d_in[5];
  const float* knb  = (const float*)d_in[6];
  float* out = (float*)d_out;

  char* p = (char*)d_ws;
  bf16_t* xb  = (bf16_t*)p;           // 16 MB, reused as ag after GEMM1
  bf16_t* ag  = xb;
  p += (size_t)16777216;
  bf16_t* wqb = (bf16_t*)p;           // 20 MB, reused as Qr after GEMM1
  bf16_t* Qr  = wqb;
  p += (size_t)20971520;
  bf16_t* wob = (bf16_t*)p; p += (size_t)8388608;
  float*  qkv = (float*)p;  p += (size_t)83886080;
  bf16_t* Kr  = (bf16_t*)p; p += (size_t)4194304;
  bf16_t* Vt  = (bf16_t*)p; p += (size_t)4194304;
  float* cosT = (float*)p;  p += (size_t)524288;
  float* sinT = (float*)p;  p += (size_t)524288;

  cvt_f32_bf16<<<8192, 256, 0, stream>>>(x, xb, 2097152);
  cvt_f32_bf16<<<10240, 256, 0, stream>>>(wqkv, wqb, 2621440);
  cvt_f32_bf16<<<4096, 256, 0, stream>>>(wo, wob, 1048576);
  rope_tables<<<512, 256, 0, stream>>>(cosT, sinT);

  // qkv = x @ w_qkv^T   (4096 x 5120 x K=2048)
  gemm_nt<<<1280, 256, 0, stream>>>(xb, wqb, qkv, 4096, 5120, 2048);

  ln_rope<<<4096, 256, 0, stream>>>(qkv, qnw, qnb, knw, knb, cosT, sinT, Qr, Kr);
  vtrans<<<512, 256, 0, stream>>>(qkv, Vt);

  attn<<<512, 256, 0, stream>>>(Qr, Kr, Vt, qkv, ag);

  // out = ag @ w_o^T    (4096 x 2048 x K=2048)
  gemm_nt<<<512, 256, 0, stream>>>(ag, wob, out, 4096, 2048, 2048);
}

// Round 4
// 354.672 us; speedup vs baseline: 1.1245x; 1.1160x over previous
//
#include <hip/hip_runtime.h>
#include <hip/hip_bf16.h>

typedef __bf16 bf16_t;
typedef __bf16 bf16x2 __attribute__((ext_vector_type(2)));
typedef __bf16 bf16x4v __attribute__((ext_vector_type(4)));
typedef __bf16 bf16x8 __attribute__((ext_vector_type(8)));
typedef float f32x4 __attribute__((ext_vector_type(4)));

#define LOG2E 1.4426950408889634f
// (1/sqrt(128)) * log2(e), folded into Q at ln_rope time
#define QSCALE (0.08838834764831843f * 1.4426950408889634f)

// ---------------- fp32 -> bf16 conversion ----------------
__global__ __launch_bounds__(256) void cvt_f32_bf16(const float* __restrict__ in,
                                                    bf16_t* __restrict__ out, int n4) {
  int i = blockIdx.x * 256 + threadIdx.x;
  if (i < n4) {
    float4 v = ((const float4*)in)[i];
    bf16x4v o;
    o[0] = (__bf16)v.x; o[1] = (__bf16)v.y; o[2] = (__bf16)v.z; o[3] = (__bf16)v.w;
    *(bf16x4v*)(out + (size_t)i * 4) = o;
  }
}

// ---------------- RoPE cos/sin tables: [S=2048][64] ----------------
__global__ __launch_bounds__(256) void rope_tables(float* __restrict__ cosT,
                                                   float* __restrict__ sinT) {
  int idx = blockIdx.x * 256 + threadIdx.x;   // 2048*64 = 131072
  int s = idx >> 6, i = idx & 63;
  float inv = __builtin_amdgcn_exp2f(-(float)i * (19.931568569324174f / 64.0f));
  float f = (float)s * inv;
  cosT[idx] = cosf(f);
  sinT[idx] = sinf(f);
}

// ---------------- bf16 NT GEMM: C[m,n] = sum_k A[m,k]*B[n,k], fp32 out ----------
__global__ __launch_bounds__(256) void gemm_nt(const bf16_t* __restrict__ A,
                                               const bf16_t* __restrict__ B,
                                               float* __restrict__ C,
                                               int M, int N, int K) {
  __shared__ bf16_t As[128 * 64];
  __shared__ bf16_t Bs[128 * 64];
  int nb = N >> 7;
  int bm = blockIdx.x / nb, bn = blockIdx.x % nb;
  int m0 = bm << 7, n0 = bn << 7;
  int tid = threadIdx.x, lane = tid & 63, wv = tid >> 6;
  int wr = wv >> 1, wc = wv & 1, lr = lane & 15, g = lane >> 4;

  f32x4 acc[4][4];
#pragma unroll
  for (int i = 0; i < 4; i++)
#pragma unroll
    for (int j = 0; j < 4; j++)
#pragma unroll
      for (int r = 0; r < 4; r++) acc[i][j][r] = 0.f;

  int srow = wv * 32 + (lane >> 3);
  int scol = (lane & 7) * 8;
  const bf16_t* aBase = A + (size_t)(m0 + srow) * K + scol;
  const bf16_t* bBase = B + (size_t)(n0 + srow) * K + scol;

  for (int k0 = 0; k0 < K; k0 += 64) {
#pragma unroll
    for (int i = 0; i < 4; i++) {
      __builtin_amdgcn_global_load_lds(
          (const __attribute__((address_space(1))) void*)(aBase + (size_t)i * 8 * K + k0),
          (__attribute__((address_space(3))) void*)&As[(wv * 32 + i * 8) * 64], 16, 0, 0);
      __builtin_amdgcn_global_load_lds(
          (const __attribute__((address_space(1))) void*)(bBase + (size_t)i * 8 * K + k0),
          (__attribute__((address_space(3))) void*)&Bs[(wv * 32 + i * 8) * 64], 16, 0, 0);
    }
    __syncthreads();
#pragma unroll
    for (int ks = 0; ks < 2; ks++) {
      bf16x8 af[4], bfv[4];
#pragma unroll
      for (int mi = 0; mi < 4; mi++)
        af[mi] = *(const bf16x8*)&As[(wr * 64 + mi * 16 + lr) * 64 + ks * 32 + g * 8];
#pragma unroll
      for (int ni = 0; ni < 4; ni++)
        bfv[ni] = *(const bf16x8*)&Bs[(wc * 64 + ni * 16 + lr) * 64 + ks * 32 + g * 8];
#pragma unroll
      for (int mi = 0; mi < 4; mi++)
#pragma unroll
        for (int ni = 0; ni < 4; ni++)
          acc[mi][ni] = __builtin_amdgcn_mfma_f32_16x16x32_bf16(af[mi], bfv[ni], acc[mi][ni], 0, 0, 0);
    }
    __syncthreads();
  }

#pragma unroll
  for (int mi = 0; mi < 4; mi++)
#pragma unroll
    for (int ni = 0; ni < 4; ni++) {
      int m = m0 + wr * 64 + mi * 16 + g * 4;
      int n = n0 + wc * 64 + ni * 16 + lr;
#pragma unroll
      for (int r = 0; r < 4; r++) C[(size_t)(m + r) * N + n] = acc[mi][ni][r];
    }
}

// ---------------- fused per-head LayerNorm + RoPE -> bf16 Q(B,H,S,D), K(B,KV,S,D) ----
// Q is pre-scaled by QSCALE so attention's QK^T lands directly in exp2-domain.
__global__ __launch_bounds__(256) void ln_rope(const float* __restrict__ qkv,
                                               const float* __restrict__ qw, const float* __restrict__ qb,
                                               const float* __restrict__ kw, const float* __restrict__ kb,
                                               const float* __restrict__ cosT, const float* __restrict__ sinT,
                                               bf16_t* __restrict__ Qr, bf16_t* __restrict__ Kr) {
  int row = blockIdx.x;              // b*2048 + s
  int b = row >> 11, s = row & 2047;
  int lane = threadIdx.x & 63, wv = threadIdx.x >> 6;
  float c = cosT[(s << 6) + lane], sn = sinT[(s << 6) + lane];
  const float* base = qkv + (size_t)row * 5120;
#pragma unroll
  for (int i = 0; i < 5; i++) {
    int head = wv * 5 + i;           // 0..15 = q heads, 16..19 = k heads
    bool isq = head < 16;
    int off = isq ? (head << 7) : (4096 + ((head - 16) << 7));
    float2 x = *(const float2*)(base + off + (lane << 1));
    float sum = x.x + x.y;
#pragma unroll
    for (int m = 1; m < 64; m <<= 1) sum += __shfl_xor(sum, m);
    float mu = sum * 0.0078125f;
    float x0 = x.x - mu, x1 = x.y - mu;
    float vs = x0 * x0 + x1 * x1;
#pragma unroll
    for (int m = 1; m < 64; m <<= 1) vs += __shfl_xor(vs, m);
    float rs = rsqrtf(vs * 0.0078125f + 1e-6f);
    const float* w = isq ? qw : kw;
    const float* bb = isq ? qb : kb;
    float y0 = x0 * rs * w[lane << 1] + bb[lane << 1];
    float y1 = x1 * rs * w[(lane << 1) + 1] + bb[(lane << 1) + 1];
    float o0 = y0 * c - y1 * sn;
    float o1 = y0 * sn + y1 * c;
    if (isq) { o0 *= QSCALE; o1 *= QSCALE; }
    bf16x2 ov; ov[0] = (__bf16)o0; ov[1] = (__bf16)o1;
    size_t dst = isq ? ((((size_t)(b * 16 + head)) * 2048 + s) * 128 + (lane << 1))
                     : ((((size_t)(b * 4 + (head - 16))) * 2048 + s) * 128 + (lane << 1));
    *(bf16x2*)((isq ? Qr : Kr) + dst) = ov;
  }
}

// ---------------- V transpose: qkv v-slice (B,S,KV,D) -> Vt (B,KV,D,S) bf16 -------
__global__ __launch_bounds__(256) void vtrans(const float* __restrict__ qkv,
                                              bf16_t* __restrict__ Vt) {
  int bid = blockIdx.x;              // ((b*4+kv)*64 + sb)
  int sb = bid & 63, kv = (bid >> 6) & 3, b = bid >> 8;
  int s0 = sb << 5;
  __shared__ bf16_t T[128 * 33];
  int tid = threadIdx.x;
#pragma unroll
  for (int i = 0; i < 16; i++) {
    int idx = i * 256 + tid;         // 0..4095
    int r = idx >> 7, d = idx & 127;
    float v = qkv[((size_t)(b * 2048 + s0 + r)) * 5120 + 4608 + (kv << 7) + d];
    T[d * 33 + r] = (__bf16)v;
  }
  __syncthreads();
#pragma unroll
  for (int j = 0; j < 16; j++) {
    int idx = j * 256 + tid;
    int d = idx >> 5, sc = idx & 31;
    Vt[(((size_t)(b * 4 + kv)) * 128 + d) * 2048 + s0 + sc] = T[d * 33 + sc];
  }
}

// ---------------- causal GQA flash attention + sigmoid gate -> ag bf16 (B,S,H*D) ----
// Softmax: lane-local common path (defer-max, per-lane lsum partials; cross-lane
// shfls only on rare rescale + once in epilogue). Only the diagonal half-tile
// (h==qg) applies the causal mask. K fragments double-banked (kA/kB) so next
// half-tile's loads are in flight during current compute.
__global__ __launch_bounds__(256) void attn(const bf16_t* __restrict__ Qr,
                                            const bf16_t* __restrict__ Kr,
                                            const bf16_t* __restrict__ Vt,
                                            const float* __restrict__ qkv,
                                            bf16_t* __restrict__ ag) {
  int bid = blockIdx.x;                 // 512 = 16h * 2b * 16jj  (jj high bits: longest first)
  int h = bid & 15, b = (bid >> 4) & 1, jj = bid >> 5;
  int kvh = h >> 2;
  int tid = threadIdx.x, lane = tid & 63, wv = tid >> 6;
  int lr = lane & 15, g = lane >> 4;
  int qg = (wv & 2) ? (63 - 2 * jj - (wv & 1)) : (2 * jj + (wv & 1));
  int qw = qg << 5;                     // wave q base (32 rows)
  int qrow0 = qw + lr, qrow1 = qrow0 + 16;
  int nh = qg + 1;                      // 32-wide kv half-tiles: kvb = 0..32*qg

  const bf16_t* Qg0 = Qr + (((size_t)(b * 16 + h)) * 2048 + qrow0) * 128;
  bf16x8 qf0[4], qf1[4];
#pragma unroll
  for (int ds = 0; ds < 4; ds++) {
    qf0[ds] = *(const bf16x8*)(Qg0 + ds * 32 + g * 8);
    qf1[ds] = *(const bf16x8*)(Qg0 + 16 * 128 + ds * 32 + g * 8);
  }
  const bf16_t* Kg = Kr + ((size_t)(b * 4 + kvh)) * 2048 * 128;
  const bf16_t* Vg = Vt + ((size_t)(b * 4 + kvh)) * 128 * 2048;

  f32x4 oa0[8], oa1[8];
#pragma unroll
  for (int i = 0; i < 8; i++)
#pragma unroll
    for (int r = 0; r < 4; r++) { oa0[i][r] = 0.f; oa1[i][r] = 0.f; }
  float mrun0 = -1e30f, mrun1 = -1e30f, lsp0 = 0.f, lsp1 = 0.f;

  int r0base = ((lr >> 2) << 3) + (lr & 3);       // pi(lr): A-row -> K-row map
  int kvlane = g << 3;                            // this lane's kv slot base within half-tile

  bf16x8 kA[8], kB[8], va[8];

  auto loadK = [&](bf16x8 (&ka)[8], int kvb) {
    const bf16_t* kp = Kg + (size_t)(kvb + r0base) * 128 + g * 8;
#pragma unroll
    for (int ds = 0; ds < 4; ds++) {
      ka[ds]     = *(const bf16x8*)(kp + ds * 32);
      ka[4 + ds] = *(const bf16x8*)(kp + 4 * 128 + ds * 32);
    }
  };

  // softmax update for one q-frag; dia = needs causal mask
  auto sm = [&](const f32x4& s0, const f32x4& s1, int qrow, int kvabs, bool dia,
                float& mrun, float& lsp, bf16x8& pb, f32x4 (&oac)[8]) {
    float tt[8];
#pragma unroll
    for (int r = 0; r < 4; r++) { tt[r] = s0[r]; tt[4 + r] = s1[r]; }
    if (dia) {
#pragma unroll
      for (int r = 0; r < 4; r++) {
        if (kvabs + r > qrow)     tt[r]     = -1e30f;
        if (kvabs + 4 + r > qrow) tt[4 + r] = -1e30f;
      }
    }
    float lm = fmaxf(fmaxf(fmaxf(tt[0], tt[1]), tt[2]),
                     fmaxf(fmaxf(tt[3], tt[4]), fmaxf(fmaxf(tt[5], tt[6]), tt[7])));
    if (__all(lm <= mrun + 8.f)) {      // defer-max common path: lane-local only
      float ps = 0.f;
#pragma unroll
      for (int i = 0; i < 8; i++) {
        float pv = __builtin_amdgcn_exp2f(tt[i] - mrun);
        pb[i] = (__bf16)pv; ps += pv;
      }
      lsp += ps;
    } else {                            // rare rescale path
      float pm = lm;
      pm = fmaxf(pm, __shfl_xor(pm, 16));
      pm = fmaxf(pm, __shfl_xor(pm, 32));
      float mnew = fmaxf(mrun, pm);
      float corr = __builtin_amdgcn_exp2f(mrun - mnew);
      float ps = 0.f;
#pragma unroll
      for (int i = 0; i < 8; i++) {
        float pv = __builtin_amdgcn_exp2f(tt[i] - mnew);
        pb[i] = (__bf16)pv; ps += pv;
      }
      lsp = lsp * corr + ps;
      mrun = mnew;
#pragma unroll
      for (int dt = 0; dt < 8; dt++)
#pragma unroll
        for (int r = 0; r < 4; r++) oac[dt][r] *= corr;
    }
  };

  auto half = [&](bf16x8 (&ka)[8], int hh) {
    int kvb = hh << 5;
    const bf16_t* vp = Vg + (size_t)lr * 2048 + kvb + g * 8;
#pragma unroll
    for (int dt = 0; dt < 8; dt++)
      va[dt] = *(const bf16x8*)(vp + (size_t)dt * 16 * 2048);
    f32x4 s00, s10, s01, s11;
#pragma unroll
    for (int r = 0; r < 4; r++) { s00[r] = 0.f; s10[r] = 0.f; s01[r] = 0.f; s11[r] = 0.f; }
    __builtin_amdgcn_s_setprio(1);
#pragma unroll
    for (int ds = 0; ds < 4; ds++) {
      s00 = __builtin_amdgcn_mfma_f32_16x16x32_bf16(ka[ds],     qf0[ds], s00, 0, 0, 0);
      s10 = __builtin_amdgcn_mfma_f32_16x16x32_bf16(ka[4 + ds], qf0[ds], s10, 0, 0, 0);
      s01 = __builtin_amdgcn_mfma_f32_16x16x32_bf16(ka[ds],     qf1[ds], s01, 0, 0, 0);
      s11 = __builtin_amdgcn_mfma_f32_16x16x32_bf16(ka[4 + ds], qf1[ds], s11, 0, 0, 0);
    }
    __builtin_amdgcn_s_setprio(0);
    int kvabs = kvb + kvlane;
    bool dia = (hh == qg);
    bf16x8 pb0, pb1;
    sm(s00, s10, qrow0, kvabs, dia, mrun0, lsp0, pb0, oa0);
    sm(s01, s11, qrow1, kvabs, dia, mrun1, lsp1, pb1, oa1);
    __builtin_amdgcn_s_setprio(1);
#pragma unroll
    for (int dt = 0; dt < 8; dt++) {
      oa0[dt] = __builtin_amdgcn_mfma_f32_16x16x32_bf16(va[dt], pb0, oa0[dt], 0, 0, 0);
      oa1[dt] = __builtin_amdgcn_mfma_f32_16x16x32_bf16(va[dt], pb1, oa1[dt], 0, 0, 0);
    }
    __builtin_amdgcn_s_setprio(0);
  };

  loadK(kA, 0);
  int hh = 0;
  for (; hh + 1 < nh; hh += 2) {
    loadK(kB, (hh + 1) << 5);
    half(kA, hh);
    if (hh + 2 < nh) loadK(kA, (hh + 2) << 5);
    half(kB, hh + 1);
  }
  if (hh < nh) half(kA, hh);

  // epilogue: row-reduce per-lane lsum partials (lanes lr, lr+16, lr+32, lr+48)
  float ls0 = lsp0 + __shfl_xor(lsp0, 16);
  ls0 += __shfl_xor(ls0, 32);
  float ls1 = lsp1 + __shfl_xor(lsp1, 16);
  ls1 += __shfl_xor(ls1, 32);
  float invl0 = __builtin_amdgcn_rcpf(ls0);
  float invl1 = __builtin_amdgcn_rcpf(ls1);

  size_t ob0 = ((size_t)b * 2048 + qrow0) * 2048 + (h << 7);
  size_t gb0 = ((size_t)b * 2048 + qrow0) * 5120 + 2048 + (h << 7);
  size_t ob1 = ((size_t)b * 2048 + qrow1) * 2048 + (h << 7);
  size_t gb1 = ((size_t)b * 2048 + qrow1) * 5120 + 2048 + (h << 7);
#pragma unroll
  for (int dt = 0; dt < 8; dt++) {
    int d = dt * 16 + (g << 2);
    float4 gt0 = *(const float4*)(qkv + gb0 + d);
    float4 gt1 = *(const float4*)(qkv + gb1 + d);
    bf16x4v o0, o1;
    o0[0] = (__bf16)(oa0[dt][0] * invl0 * __builtin_amdgcn_rcpf(1.f + __builtin_amdgcn_exp2f(-gt0.x * LOG2E)));
    o0[1] = (__bf16)(oa0[dt][1] * invl0 * __builtin_amdgcn_rcpf(1.f + __builtin_amdgcn_exp2f(-gt0.y * LOG2E)));
    o0[2] = (__bf16)(oa0[dt][2] * invl0 * __builtin_amdgcn_rcpf(1.f + __builtin_amdgcn_exp2f(-gt0.z * LOG2E)));
    o0[3] = (__bf16)(oa0[dt][3] * invl0 * __builtin_amdgcn_rcpf(1.f + __builtin_amdgcn_exp2f(-gt0.w * LOG2E)));
    o1[0] = (__bf16)(oa1[dt][0] * invl1 * __builtin_amdgcn_rcpf(1.f + __builtin_amdgcn_exp2f(-gt1.x * LOG2E)));
    o1[1] = (__bf16)(oa1[dt][1] * invl1 * __builtin_amdgcn_rcpf(1.f + __builtin_amdgcn_exp2f(-gt1.y * LOG2E)));
    o1[2] = (__bf16)(oa1[dt][2] * invl1 * __builtin_amdgcn_rcpf(1.f + __builtin_amdgcn_exp2f(-gt1.z * LOG2E)));
    o1[3] = (__bf16)(oa1[dt][3] * invl1 * __builtin_amdgcn_rcpf(1.f + __builtin_amdgcn_exp2f(-gt1.w * LOG2E)));
    *(bf16x4v*)(ag + ob0 + d) = o0;
    *(bf16x4v*)(ag + ob1 + d) = o1;
  }
}

// ---------------- launch ----------------
extern "C" void kernel_launch(void* const* d_in, const int* in_sizes, int n_in,
                              void* d_out, int out_size, void* d_ws, size_t ws_size,
                              hipStream_t stream) {
  const float* x    = (const float*)d_in[0];
  const float* wqkv = (const float*)d_in[1];
  const float* wo   = (const float*)d_in[2];
  const float* qnw  = (const float*)d_in[3];
  const float* qnb  = (const float*)d_in[4];
  const float* knw  = (const float*)d_in[5];
  const float* knb  = (const float*)d_in[6];
  float* out = (float*)d_out;

  char* p = (char*)d_ws;
  bf16_t* xb  = (bf16_t*)p;           // 16 MB, reused as ag after GEMM1
  bf16_t* ag  = xb;
  p += (size_t)16777216;
  bf16_t* wqb = (bf16_t*)p;           // 20 MB, reused as Qr after GEMM1
  bf16_t* Qr  = wqb;
  p += (size_t)20971520;
  bf16_t* wob = (bf16_t*)p; p += (size_t)8388608;
  float*  qkv = (float*)p;  p += (size_t)83886080;
  bf16_t* Kr  = (bf16_t*)p; p += (size_t)4194304;
  bf16_t* Vt  = (bf16_t*)p; p += (size_t)4194304;
  float* cosT = (float*)p;  p += (size_t)524288;
  float* sinT = (float*)p;  p += (size_t)524288;

  cvt_f32_bf16<<<8192, 256, 0, stream>>>(x, xb, 2097152);
  cvt_f32_bf16<<<10240, 256, 0, stream>>>(wqkv, wqb, 2621440);
  cvt_f32_bf16<<<4096, 256, 0, stream>>>(wo, wob, 1048576);
  rope_tables<<<512, 256, 0, stream>>>(cosT, sinT);

  // qkv = x @ w_qkv^T   (4096 x 5120 x K=2048)
  gemm_nt<<<1280, 256, 0, stream>>>(xb, wqb, qkv, 4096, 5120, 2048);

  ln_rope<<<4096, 256, 0, stream>>>(qkv, qnw, qnb, knw, knb, cosT, sinT, Qr, Kr);
  vtrans<<<512, 256, 0, stream>>>(qkv, Vt);

  attn<<<512, 256, 0, stream>>>(Qr, Kr, Vt, qkv, ag);

  // out = ag @ w_o^T    (4096 x 2048 x K=2048)
  gemm_nt<<<512, 256, 0, stream>>>(ag, wob, out, 4096, 2048, 2048);
}